// Round 7
// baseline (391.025 us; speedup 1.0000x reference)
//
#include <hip/hip_runtime.h>
#include <math.h>

#define N_NODES 50000
#define N_EDGES 800000
#define DIM 256
#define SCAN_BLOCKS ((N_NODES + 255) / 256)   // 196
#define NXBLK 12500                           // (N_NODES*DIM/4)/256 blocks for x convert
#define NDEGBLK ((N_EDGES + 255) / 256)       // 3125
#define ROWS 128
#define GBLK ((N_NODES + ROWS - 1) / ROWS)    // 391

typedef short bf16x8 __attribute__((ext_vector_type(8)));
typedef float f32x4 __attribute__((ext_vector_type(4)));

__device__ __forceinline__ float bf2f(unsigned short u) {
    return __uint_as_float(((unsigned)u) << 16);
}
__device__ __forceinline__ unsigned short f2bf(float f) {
    unsigned u = __float_as_uint(f);
    return (unsigned short)((u + 0x7fffu + ((u >> 16) & 1u)) >> 16);  // RTNE
}

// ---- fused prologue: x->bf16 + W1/W2 transpose + deg_count (ideg pre-zeroed via memset) ----
__global__ __launch_bounds__(256) void k_prep(const float* __restrict__ x,
                                              unsigned short* __restrict__ xb,
                                              const float* __restrict__ W1,
                                              unsigned short* __restrict__ W1t,
                                              const float* __restrict__ W2,
                                              unsigned short* __restrict__ W2t,
                                              const int* __restrict__ dst,
                                              int* __restrict__ ideg) {
    int bid = blockIdx.x;
    int tid = threadIdx.x;
    if (bid < NXBLK) {
        int i = bid * 256 + tid;              // one float4 per thread
        float4 v = ((const float4*)x)[i];
        ((ushort4*)xb)[i] = make_ushort4(f2bf(v.x), f2bf(v.y), f2bf(v.z), f2bf(v.w));
    } else if (bid < NXBLK + 256) {
        int n = bid - NXBLK;
        W1t[n * 256 + tid] = f2bf(W1[tid * 256 + n]);
    } else if (bid < NXBLK + 512) {
        int n = bid - NXBLK - 256;
        W2t[n * 256 + tid] = f2bf(W2[tid * 256 + n]);
    } else {
        int e = (bid - NXBLK - 512) * 256 + tid;
        if (e < N_EDGES) atomicAdd(&ideg[dst[e]], 1);
    }
}

// ---------------- CSR build ----------------

__global__ __launch_bounds__(256) void k_scan_block(const int* __restrict__ ideg,
                                                    int* __restrict__ rowptr,
                                                    int* __restrict__ blocksum) {
    __shared__ int s[256];
    int t = threadIdx.x;
    int i = blockIdx.x * 256 + t;
    int v = (i < N_NODES) ? ideg[i] : 0;
    s[t] = v;
    for (int off = 1; off < 256; off <<= 1) {
        __syncthreads();
        int add = (t >= off) ? s[t - off] : 0;
        __syncthreads();
        s[t] += add;
    }
    __syncthreads();
    if (i < N_NODES) rowptr[i] = s[t] - v;
    if (t == 255) blocksum[blockIdx.x] = s[255];
}

// tops-scan (redundant per block, LDS) + global offsets + cursor + dis
__global__ __launch_bounds__(256) void k_scan_add(int* __restrict__ rowptr,
                                                  const int* __restrict__ blocksum,
                                                  int* __restrict__ cursor,
                                                  const int* __restrict__ ideg,
                                                  float* __restrict__ dis) {
    __shared__ int s[256];
    int t = threadIdx.x;
    int v = (t < SCAN_BLOCKS) ? blocksum[t] : 0;
    s[t] = v;
    for (int off = 1; off < 256; off <<= 1) {
        __syncthreads();
        int add = (t >= off) ? s[t - off] : 0;
        __syncthreads();
        s[t] += add;
    }
    __syncthreads();
    int excl = s[t] - v;
    __syncthreads();
    s[t] = excl;
    __syncthreads();
    int off = s[blockIdx.x];

    int i = blockIdx.x * 256 + t;
    if (i < N_NODES) {
        int r = rowptr[i] + off;
        rowptr[i] = r;
        cursor[i] = r;
        dis[i] = rsqrtf((float)(ideg[i] + 1));
    }
    if (i == 0) rowptr[N_NODES] = N_EDGES;
}

__global__ void k_csr_fill(const int* __restrict__ src, const int* __restrict__ dst,
                           int* __restrict__ cursor, int* __restrict__ csr_src) {
    int e = blockIdx.x * blockDim.x + threadIdx.x;
    if (e < N_EDGES) {
        int pos = atomicAdd(&cursor[dst[e]], 1);
        csr_src[pos] = src[e];
    }
}

// ---------------- fused aggregate + MFMA GEMM (+ optional FC/log_softmax) ----------------
// Phase 1: gather-aggregate 128 rows x 256 cols into swizzled LDS A-tile.
// Phase 2: C = relu(A @ W + b); FC=0 -> write bf16 C; FC=1 -> logits + log_softmax.
template <int FC>
__global__ __launch_bounds__(512) void k_fused(const unsigned short* __restrict__ in,
                                               const float* __restrict__ dis,
                                               const int* __restrict__ rowptr,
                                               const int* __restrict__ csr_src,
                                               const unsigned short* __restrict__ Wt,
                                               const float* __restrict__ bias,
                                               const float* __restrict__ Wfc,
                                               const float* __restrict__ bfc,
                                               unsigned short* __restrict__ outB,
                                               float* __restrict__ outF) {
    __shared__ unsigned short As[ROWS * DIM];   // 64 KB, XOR-swizzled rows of 512 B
    __shared__ unsigned short Bs[4][256][8];    // 16 KB (k-chunked W tile; reused as f32 scratch)

    int tid = threadIdx.x;
    int lane = tid & 63;
    int wave = tid >> 6;          // 0..7
    int rowBase = blockIdx.x * ROWS;

    // ---- phase 1: each wave aggregates 16 rows (full 256-col row per step) ----
    for (int i = 0; i < 16; ++i) {
        int rl = wave * 16 + i;
        int node = rowBase + rl;
        float a0 = 0.f, a1 = 0.f, a2 = 0.f, a3 = 0.f;
        if (node < N_NODES) {
            int f = lane * 4;
            float dn = dis[node];
            ushort4 sv = *(const ushort4*)(in + (size_t)node * DIM + f);
            a0 = dn * bf2f(sv.x);
            a1 = dn * bf2f(sv.y);
            a2 = dn * bf2f(sv.z);
            a3 = dn * bf2f(sv.w);
            int e = rowptr[node];
            int eEnd = rowptr[node + 1];
            for (; e + 3 < eEnd; e += 4) {
                int s0 = csr_src[e], s1 = csr_src[e + 1], s2 = csr_src[e + 2], s3 = csr_src[e + 3];
                float w0 = dis[s0], w1 = dis[s1], w2 = dis[s2], w3 = dis[s3];
                ushort4 v0 = *(const ushort4*)(in + (size_t)s0 * DIM + f);
                ushort4 v1 = *(const ushort4*)(in + (size_t)s1 * DIM + f);
                ushort4 v2 = *(const ushort4*)(in + (size_t)s2 * DIM + f);
                ushort4 v3 = *(const ushort4*)(in + (size_t)s3 * DIM + f);
                a0 += w0 * bf2f(v0.x) + w1 * bf2f(v1.x) + w2 * bf2f(v2.x) + w3 * bf2f(v3.x);
                a1 += w0 * bf2f(v0.y) + w1 * bf2f(v1.y) + w2 * bf2f(v2.y) + w3 * bf2f(v3.y);
                a2 += w0 * bf2f(v0.z) + w1 * bf2f(v1.z) + w2 * bf2f(v2.z) + w3 * bf2f(v3.z);
                a3 += w0 * bf2f(v0.w) + w1 * bf2f(v1.w) + w2 * bf2f(v2.w) + w3 * bf2f(v3.w);
            }
            for (; e < eEnd; ++e) {
                int s0 = csr_src[e];
                float w0 = dis[s0];
                ushort4 v0 = *(const ushort4*)(in + (size_t)s0 * DIM + f);
                a0 += w0 * bf2f(v0.x);
                a1 += w0 * bf2f(v0.y);
                a2 += w0 * bf2f(v0.z);
                a3 += w0 * bf2f(v0.w);
            }
            a0 *= dn; a1 *= dn; a2 *= dn; a3 *= dn;
        }
        // swizzled store: all 64 lanes same row -> conflict-free
        unsigned off = (unsigned)rl * 512u + (((unsigned)lane * 8u) ^ (((unsigned)rl & 15u) << 4));
        *(ushort4*)((char*)As + off) = make_ushort4(f2bf(a0), f2bf(a1), f2bf(a2), f2bf(a3));
    }
    __syncthreads();

    // ---- phase 2: MFMA K-loop ----
    int wm = wave >> 1;           // 0..3 (32-row group)
    int wn = wave & 1;            // 0..1 (128-col half)
    int lr = lane & 15;
    int lc = lane >> 4;

    f32x4 acc[2][8] = {};

    int brow = tid >> 1;          // 0..255
    int cc = (tid & 1) * 2;       // chunks cc, cc+1

    for (int k0 = 0; k0 < DIM; k0 += 32) {
        *(float4*)&Bs[cc][brow][0]     = *(const float4*)(Wt + (size_t)brow * DIM + k0 + cc * 8);
        *(float4*)&Bs[cc + 1][brow][0] = *(const float4*)(Wt + (size_t)brow * DIM + k0 + cc * 8 + 8);
        __syncthreads();

        int r0 = wm * 32 + lr;
        int r1 = r0 + 16;
        unsigned cb = (unsigned)(k0 * 2 + lc * 16);
        bf16x8 af0 = *(const bf16x8*)((const char*)As + (unsigned)r0 * 512u + (cb ^ (((unsigned)r0 & 15u) << 4)));
        bf16x8 af1 = *(const bf16x8*)((const char*)As + (unsigned)r1 * 512u + (cb ^ (((unsigned)r1 & 15u) << 4)));
#pragma unroll
        for (int n = 0; n < 8; ++n) {
            bf16x8 bfr = *(const bf16x8*)&Bs[lc][wn * 128 + n * 16 + lr][0];
            acc[0][n] = __builtin_amdgcn_mfma_f32_16x16x32_bf16(af0, bfr, acc[0][n], 0, 0, 0);
            acc[1][n] = __builtin_amdgcn_mfma_f32_16x16x32_bf16(af1, bfr, acc[1][n], 0, 0, 0);
        }
        __syncthreads();
    }

    if (FC) {
        // fused FC (256->2) + log_softmax; h2 stays f32 in regs
        float bv[8], wf0[8], wf1[8];
#pragma unroll
        for (int n = 0; n < 8; ++n) {
            int col = wn * 128 + n * 16 + lr;
            bv[n]  = bias[col];
            wf0[n] = Wfc[col * 2 + 0];
            wf1[n] = Wfc[col * 2 + 1];
        }
        float* part = (float*)&Bs[0][0][0];   // [128][2 wn][2] f32, reuse Bs
#pragma unroll
        for (int m = 0; m < 2; ++m) {
#pragma unroll
            for (int reg = 0; reg < 4; ++reg) {
                int rl = wm * 32 + m * 16 + lc * 4 + reg;
                float s0 = 0.f, s1 = 0.f;
#pragma unroll
                for (int n = 0; n < 8; ++n) {
                    float v = fmaxf(acc[m][n][reg] + bv[n], 0.f);
                    s0 += v * wf0[n];
                    s1 += v * wf1[n];
                }
#pragma unroll
                for (int o = 1; o < 16; o <<= 1) {
                    s0 += __shfl_xor(s0, o);
                    s1 += __shfl_xor(s1, o);
                }
                if (lr == 0) {
                    part[rl * 4 + wn * 2 + 0] = s0;
                    part[rl * 4 + wn * 2 + 1] = s1;
                }
            }
        }
        __syncthreads();
        if (tid < ROWS) {
            int row = rowBase + tid;
            if (row < N_NODES) {
                float l0 = part[tid * 4 + 0] + part[tid * 4 + 2] + bfc[0];
                float l1 = part[tid * 4 + 1] + part[tid * 4 + 3] + bfc[1];
                float mx = fmaxf(l0, l1);
                float lse = mx + logf(expf(l0 - mx) + expf(l1 - mx));
                outF[(size_t)row * 2 + 0] = l0 - lse;
                outF[(size_t)row * 2 + 1] = l1 - lse;
            }
        }
    } else {
        float bv[8];
#pragma unroll
        for (int n = 0; n < 8; ++n) bv[n] = bias[wn * 128 + n * 16 + lr];
#pragma unroll
        for (int m = 0; m < 2; ++m) {
#pragma unroll
            for (int reg = 0; reg < 4; ++reg) {
                int row = rowBase + wm * 32 + m * 16 + lc * 4 + reg;
                if (row < N_NODES) {
#pragma unroll
                    for (int n = 0; n < 8; ++n) {
                        float v = fmaxf(acc[m][n][reg] + bv[n], 0.f);
                        outB[(size_t)row * DIM + wn * 128 + n * 16 + lr] = f2bf(v);
                    }
                }
            }
        }
    }
}

// ---------------- launch ----------------
extern "C" void kernel_launch(void* const* d_in, const int* in_sizes, int n_in,
                              void* d_out, int out_size, void* d_ws, size_t ws_size,
                              hipStream_t stream) {
    const float* x      = (const float*)d_in[0];
    const int* ei       = (const int*)d_in[1];   // int32 from harness
    const int* esrc     = ei;
    const int* edst     = ei + N_EDGES;
    const float* W1  = (const float*)d_in[2];
    const float* b1  = (const float*)d_in[3];
    const float* W2  = (const float*)d_in[4];
    const float* b2  = (const float*)d_in[5];
    const float* Wfc = (const float*)d_in[6];
    const float* bfc = (const float*)d_in[7];
    float* out = (float*)d_out;

    const size_t NF = (size_t)N_NODES * DIM;
    unsigned short* P0 = (unsigned short*)d_ws;          // xb
    unsigned short* P1 = P0 + NF;                        // h1b
    unsigned short* W1t = P1 + NF;                       // 256*256
    unsigned short* W2t = W1t + 256 * 256;
    float* dis    = (float*)(W2t + 256 * 256);           // N
    int* ideg     = (int*)(dis + N_NODES);               // N
    int* rowptr   = ideg + N_NODES;                      // N+1
    int* cursor   = rowptr + N_NODES + 1;                // N
    int* blocksum = cursor + N_NODES;                    // 256
    int* csr_src  = blocksum + 256;                      // E

    // CSR build + converts
    hipMemsetAsync(ideg, 0, N_NODES * sizeof(int), stream);
    k_prep<<<NXBLK + 512 + NDEGBLK, 256, 0, stream>>>(x, P0, W1, W1t, W2, W2t, edst, ideg);
    k_scan_block<<<SCAN_BLOCKS, 256, 0, stream>>>(ideg, rowptr, blocksum);
    k_scan_add<<<SCAN_BLOCKS, 256, 0, stream>>>(rowptr, blocksum, cursor, ideg, dis);
    k_csr_fill<<<(N_EDGES + 255) / 256, 256, 0, stream>>>(esrc, edst, cursor, csr_src);

    // layer 1 (fused agg + gemm + relu)
    k_fused<0><<<GBLK, 512, 0, stream>>>(P0, dis, rowptr, csr_src, W1t, b1,
                                         (const float*)nullptr, (const float*)nullptr,
                                         P1, (float*)nullptr);
    // layer 2 (fused agg + gemm + relu + FC + log_softmax)
    k_fused<1><<<GBLK, 512, 0, stream>>>(P1, dis, rowptr, csr_src, W2t, b2,
                                         Wfc, bfc,
                                         (unsigned short*)nullptr, out);
}